// Round 1
// baseline (2337.872 us; speedup 1.0000x reference)
//
#include <hip/hip_runtime.h>
#include <math.h>

#define NB   4
#define NT   500
#define NF   65
#define NC   128
#define NH   8
#define NE   4
#define NV   16
#define NCTX 10
#define DQ   260    // NF*NE
#define DV   1040   // NF*NV
#define DP   8320   // NF*NC

// ---------------- Q/K projection: 128 -> 32, PReLU, write [bh][d=f*4+e][t] ----------------
__global__ __launch_bounds__(256) void proj32_k(const float* __restrict__ x,
    const float* __restrict__ W, const float* __restrict__ bias,
    const float* __restrict__ a, float* __restrict__ out)
{
    __shared__ float Wl[32 * 128];
    int bf = blockIdx.x; int b = bf / NF, f = bf % NF;
    int t = blockIdx.y * 256 + threadIdx.x;
    for (int i = threadIdx.x; i < 32 * 128; i += 256) Wl[i] = W[i];
    __syncthreads();
    if (t >= NT) return;
    float acc[32];
#pragma unroll
    for (int o = 0; o < 32; o++) acc[o] = 0.f;
    const float* xp = x + (size_t)(b * NC * NF + f) * NT + t;
    for (int c = 0; c < NC; c++) {
        float xv = xp[(size_t)c * NF * NT];
#pragma unroll
        for (int o = 0; o < 32; o++) acc[o] += xv * Wl[o * 128 + c];
    }
    float av = a[0];
#pragma unroll
    for (int o = 0; o < 32; o++) {
        float y = acc[o] + bias[o];
        y = (y >= 0.f) ? y : av * y;
        int h = o >> 2, e = o & 3;
        out[(size_t)((b * NH + h) * DQ + f * NE + e) * NT + t] = y;
    }
}

// ---------------- V projection: 128 -> 128 (64 per block), PReLU, write [bh][d=f*16+v][t] ----------------
__global__ __launch_bounds__(256) void projV_k(const float* __restrict__ x,
    const float* __restrict__ W, const float* __restrict__ bias,
    const float* __restrict__ a, float* __restrict__ out)
{
    __shared__ float Wl[64 * 128];
    int bf = blockIdx.x; int b = bf / NF, f = bf % NF;
    int t = blockIdx.y * 256 + threadIdx.x;
    int o0 = blockIdx.z * 64;
    for (int i = threadIdx.x; i < 64 * 128; i += 256) Wl[i] = W[o0 * 128 + i];
    __syncthreads();
    if (t >= NT) return;
    float acc[64];
#pragma unroll
    for (int o = 0; o < 64; o++) acc[o] = 0.f;
    const float* xp = x + (size_t)(b * NC * NF + f) * NT + t;
    for (int c = 0; c < NC; c++) {
        float xv = xp[(size_t)c * NF * NT];
#pragma unroll
        for (int o = 0; o < 64; o++) acc[o] += xv * Wl[o * 128 + c];
    }
    float av = a[0];
#pragma unroll
    for (int o = 0; o < 64; o++) {
        int oo = o0 + o;
        float y = acc[o] + bias[oo];
        y = (y >= 0.f) ? y : av * y;
        int h = oo >> 4, v = oo & 15;
        out[(size_t)((b * NH + h) * DV + f * NV + v) * NT + t] = y;
    }
}

// ---------------- P projection: z(from VoT) 128 -> 128 (64 per block), PReLU, write yraw[b][o][f][t] ----------------
__global__ __launch_bounds__(256) void projP_k(const float* __restrict__ VoT,
    const float* __restrict__ W, const float* __restrict__ bias,
    const float* __restrict__ a, float* __restrict__ yraw)
{
    __shared__ float Wl[64 * 128];
    int bf = blockIdx.x; int b = bf / NF, f = bf % NF;
    int t = blockIdx.y * 256 + threadIdx.x;
    int o0 = blockIdx.z * 64;
    for (int i = threadIdx.x; i < 64 * 128; i += 256) Wl[i] = W[o0 * 128 + i];
    __syncthreads();
    if (t >= NT) return;
    float acc[64];
#pragma unroll
    for (int o = 0; o < 64; o++) acc[o] = 0.f;
    for (int cp = 0; cp < NC; cp++) {
        int h = cp >> 4, v = cp & 15;
        float zv = VoT[(size_t)((b * NH + h) * DV + f * NV + v) * NT + t];
#pragma unroll
        for (int o = 0; o < 64; o++) acc[o] += zv * Wl[o * 128 + cp];
    }
    float av = a[0];
#pragma unroll
    for (int o = 0; o < 64; o++) {
        int oo = o0 + o;
        float y = acc[o] + bias[oo];
        y = (y >= 0.f) ? y : av * y;
        yraw[(size_t)((b * NC + oo) * NF + f) * NT + t] = y;
    }
}

// ---------------- LayerNorm over d (buf is [bh][d][t]), in place ----------------
__global__ __launch_bounds__(256) void ln_k(float* __restrict__ buf,
    const float* __restrict__ g, const float* __restrict__ be, int D)
{
    int bh = blockIdx.x;
    int t = blockIdx.y * 256 + threadIdx.x;
    if (t >= NT) return;
    float* p0 = buf + (size_t)bh * D * NT + t;
    float s = 0.f, s2 = 0.f;
    for (int d = 0; d < D; d++) { float v = p0[(size_t)d * NT]; s += v; s2 += v * v; }
    float inv = 1.0f / (float)D;
    float mu = s * inv;
    float var = s2 * inv - mu * mu;
    float rstd = rsqrtf(var + 1e-5f);
    for (int d = 0; d < D; d++) {
        float v = p0[(size_t)d * NT];
        p0[(size_t)d * NT] = (v - mu) * rstd * g[d] + be[d];
    }
}

// ---------------- K_buf_new / V_buf_new: last 9 time rows of LN'd K, V ----------------
__global__ void copybuf_k(const float* __restrict__ Kt, const float* __restrict__ Vt,
                          float* __restrict__ outK, float* __restrict__ outV)
{
    int i = blockIdx.x * 256 + threadIdx.x;
    const int NK = 32 * 9 * DQ;
    const int NVb = 32 * 9 * DV;
    if (i < NK) {
        int bh = i / (9 * DQ); int r = i % (9 * DQ); int j = r / DQ; int d = r % DQ;
        outK[i] = Kt[(size_t)(bh * DQ + d) * NT + 491 + j];
    } else if (i < NK + NVb) {
        int i2 = i - NK;
        int bh = i2 / (9 * DV); int r = i2 % (9 * DV); int j = r / DV; int d = r % DV;
        outV[i2] = Vt[(size_t)(bh * DV + d) * NT + 491 + j];
    }
}

// ---------------- scores + softmax: p[bh][c][t] ----------------
__global__ __launch_bounds__(256) void scores_k(const float* __restrict__ Qt,
    const float* __restrict__ Kt, const float* __restrict__ Kbuf, float* __restrict__ p)
{
    int bh = blockIdx.x;
    int t = blockIdx.y * 256 + threadIdx.x;
    if (t >= NT) return;
    float s[NCTX];
#pragma unroll
    for (int c = 0; c < NCTX; c++) s[c] = 0.f;
    const float* q = Qt + (size_t)bh * DQ * NT + t;
    if (t >= NCTX - 1) {
        const float* kb = Kt + (size_t)bh * DQ * NT + (t - (NCTX - 1));
        for (int d = 0; d < DQ; d++) {
            float qv = q[(size_t)d * NT];
            const float* kr = kb + (size_t)d * NT;
#pragma unroll
            for (int c = 0; c < NCTX; c++) s[c] += qv * kr[c];
        }
    } else {
        for (int d = 0; d < DQ; d++) {
            float qv = q[(size_t)d * NT];
#pragma unroll
            for (int c = 0; c < NCTX; c++) {
                int tc = t + c;
                float kv = (tc < NCTX - 1) ? Kbuf[(size_t)(bh * (NCTX - 1) + tc) * DQ + d]
                                           : Kt[(size_t)(bh * DQ + d) * NT + (tc - (NCTX - 1))];
                s[c] += qv * kv;
            }
        }
    }
    const float sc = 0.06201736729460423f; // 1/sqrt(260)
    float m = -1e30f;
#pragma unroll
    for (int c = 0; c < NCTX; c++) { s[c] *= sc; m = fmaxf(m, s[c]); }
    float den = 0.f;
#pragma unroll
    for (int c = 0; c < NCTX; c++) { s[c] = __expf(s[c] - m); den += s[c]; }
    float iden = 1.0f / den;
#pragma unroll
    for (int c = 0; c < NCTX; c++) p[(size_t)(bh * NCTX + c) * NT + t] = s[c] * iden;
}

// ---------------- Vo = sum_c p[c] * Vfull[t+c] : VoT[bh][d][t] ----------------
__global__ __launch_bounds__(256) void vo_k(const float* __restrict__ p,
    const float* __restrict__ Vt, const float* __restrict__ Vbuf, float* __restrict__ VoT)
{
    int bh = blockIdx.x;
    int t = blockIdx.y * 256 + threadIdx.x;
    if (t >= NT) return;
    float pc[NCTX];
#pragma unroll
    for (int c = 0; c < NCTX; c++) pc[c] = p[(size_t)(bh * NCTX + c) * NT + t];
    if (t >= NCTX - 1) {
        const float* vb = Vt + (size_t)bh * DV * NT + (t - (NCTX - 1));
        for (int d = 0; d < DV; d++) {
            const float* vr = vb + (size_t)d * NT;
            float acc = 0.f;
#pragma unroll
            for (int c = 0; c < NCTX; c++) acc += pc[c] * vr[c];
            VoT[(size_t)(bh * DV + d) * NT + t] = acc;
        }
    } else {
        for (int d = 0; d < DV; d++) {
            float acc = 0.f;
#pragma unroll
            for (int c = 0; c < NCTX; c++) {
                int tc = t + c;
                float v = (tc < NCTX - 1) ? Vbuf[(size_t)(bh * (NCTX - 1) + tc) * DV + d]
                                          : Vt[(size_t)(bh * DV + d) * NT + (tc - (NCTX - 1))];
                acc += pc[c] * v;
            }
            VoT[(size_t)(bh * DV + d) * NT + t] = acc;
        }
    }
}

// ---------------- Final LN over 8320 (per b,t): partial sums ----------------
__global__ __launch_bounds__(256) void lnp_s1(const float* __restrict__ yraw,
    float* __restrict__ partS, float* __restrict__ partS2)
{
    int b = blockIdx.x;
    int t = blockIdx.y * 256 + threadIdx.x;
    int ch = blockIdx.z;
    if (t >= NT) return;
    float s = 0.f, s2 = 0.f;
    int i0 = ch * 520;
    for (int k = 0; k < 520; k++) {
        int i = i0 + k;
        int f = i >> 7, o = i & 127;
        float v = yraw[(size_t)((b * NC + o) * NF + f) * NT + t];
        s += v; s2 += v * v;
    }
    partS[(size_t)(b * 16 + ch) * NT + t] = s;
    partS2[(size_t)(b * 16 + ch) * NT + t] = s2;
}

__global__ __launch_bounds__(256) void lnp_s2(const float* __restrict__ partS,
    const float* __restrict__ partS2, float* __restrict__ muA, float* __restrict__ rstdA)
{
    int b = blockIdx.x;
    int t = blockIdx.y * 256 + threadIdx.x;
    if (t >= NT) return;
    float s = 0.f, s2 = 0.f;
    for (int ch = 0; ch < 16; ch++) {
        s += partS[(size_t)(b * 16 + ch) * NT + t];
        s2 += partS2[(size_t)(b * 16 + ch) * NT + t];
    }
    float inv = 1.0f / (float)DP;
    float mu = s * inv;
    float var = s2 * inv - mu * mu;
    muA[b * NT + t] = mu;
    rstdA[b * NT + t] = rsqrtf(var + 1e-5f);
}

// ---------------- apply LN + residual, output [b][o][f][t] ----------------
__global__ __launch_bounds__(256) void lnp_apply(const float* __restrict__ yraw,
    const float* __restrict__ x, const float* __restrict__ g, const float* __restrict__ be,
    const float* __restrict__ muA, const float* __restrict__ rstdA, float* __restrict__ out)
{
    int bo = blockIdx.x; int b = bo >> 7, o = bo & 127;
    int t = blockIdx.y * 256 + threadIdx.x;
    if (t >= NT) return;
    float mu = muA[b * NT + t], rstd = rstdA[b * NT + t];
    for (int f = 0; f < NF; f++) {
        size_t idx = (size_t)((b * NC + o) * NF + f) * NT + t;
        int i = f * NC + o;
        float v = yraw[idx];
        out[idx] = (v - mu) * rstd * g[i] + be[i] + x[idx];
    }
}

extern "C" void kernel_launch(void* const* d_in, const int* in_sizes, int n_in,
                              void* d_out, int out_size, void* d_ws, size_t ws_size,
                              hipStream_t stream) {
    const float* x    = (const float*)d_in[0];
    const float* mc   = (const float*)d_in[1];
    const float* Kbuf = (const float*)d_in[2];
    const float* Vbuf = (const float*)d_in[3];
    const float* W_Q  = (const float*)d_in[4];
    const float* b_Q  = (const float*)d_in[5];
    const float* a_Q  = (const float*)d_in[6];
    const float* g_Q  = (const float*)d_in[7];
    const float* be_Q = (const float*)d_in[8];
    const float* W_K  = (const float*)d_in[9];
    const float* b_K  = (const float*)d_in[10];
    const float* a_K  = (const float*)d_in[11];
    const float* g_K  = (const float*)d_in[12];
    const float* be_K = (const float*)d_in[13];
    const float* W_V  = (const float*)d_in[14];
    const float* b_V  = (const float*)d_in[15];
    const float* a_V  = (const float*)d_in[16];
    const float* g_V  = (const float*)d_in[17];
    const float* be_V = (const float*)d_in[18];
    const float* W_P  = (const float*)d_in[19];
    const float* b_P  = (const float*)d_in[20];
    const float* a_P  = (const float*)d_in[21];
    const float* g_P  = (const float*)d_in[22];
    const float* be_P = (const float*)d_in[23];

    float* out  = (float*)d_out;                       // (4,128,65,500)
    float* outK = out + (size_t)NB * NC * NF * NT;     // +16,640,000
    float* outV = outK + 32 * 9 * DQ;                  // +74,880

    float* ws = (float*)d_ws;
    float* Qt     = ws;                                // 4,160,000
    float* Kt     = Qt + (size_t)32 * DQ * NT;         // 4,160,000
    float* Vt     = Kt + (size_t)32 * DQ * NT;         // 16,640,000
    float* VoT    = Vt + (size_t)32 * DV * NT;         // 16,640,000
    float* pbuf   = VoT + (size_t)32 * DV * NT;        // 160,000
    float* partS  = pbuf + (size_t)32 * NCTX * NT;     // 32,000
    float* partS2 = partS + 32000;                     // 32,000
    float* muA    = partS2 + 32000;                    // 2,000
    float* rstdA  = muA + 2000;                        // 2,000
    float* yraw   = Vt;  // alias: Vt dead after vo_k

    dim3 blk(256);
    const int TCH = (NT + 255) / 256;  // 2

    proj32_k<<<dim3(NB * NF, TCH), blk, 0, stream>>>(x,  W_Q, b_Q, a_Q, Qt);
    proj32_k<<<dim3(NB * NF, TCH), blk, 0, stream>>>(mc, W_K, b_K, a_K, Kt);
    projV_k <<<dim3(NB * NF, TCH, 2), blk, 0, stream>>>(mc, W_V, b_V, a_V, Vt);

    ln_k<<<dim3(32, TCH), blk, 0, stream>>>(Qt, g_Q, be_Q, DQ);
    ln_k<<<dim3(32, TCH), blk, 0, stream>>>(Kt, g_K, be_K, DQ);
    ln_k<<<dim3(32, TCH), blk, 0, stream>>>(Vt, g_V, be_V, DV);

    int nbuf = 32 * 9 * DQ + 32 * 9 * DV;
    copybuf_k<<<dim3((nbuf + 255) / 256), blk, 0, stream>>>(Kt, Vt, outK, outV);

    scores_k<<<dim3(32, TCH), blk, 0, stream>>>(Qt, Kt, Kbuf, pbuf);
    vo_k    <<<dim3(32, TCH), blk, 0, stream>>>(pbuf, Vt, Vbuf, VoT);

    projP_k<<<dim3(NB * NF, TCH, 2), blk, 0, stream>>>(VoT, W_P, b_P, a_P, yraw);

    lnp_s1   <<<dim3(NB, TCH, 16), blk, 0, stream>>>(yraw, partS, partS2);
    lnp_s2   <<<dim3(NB, TCH), blk, 0, stream>>>(partS, partS2, muA, rstdA);
    lnp_apply<<<dim3(NB * NC, TCH), blk, 0, stream>>>(yraw, x, g_P, be_P, muA, rstdA, out);
}

// Round 2
// 939.102 us; speedup vs baseline: 2.4895x; 2.4895x over previous
//
#include <hip/hip_runtime.h>
#include <math.h>

#define NB   4
#define NT   500
#define NF   65
#define NC   128
#define NH   8
#define NE   4
#define NV   16
#define NCTX 10
#define DQ   260    // NF*NE
#define DV   1040   // NF*NV
#define DP   8320   // NF*NC

// ---------------- Q/K projection: 128 -> 32, PReLU, write [bh][d=f*4+e][t] ----------------
__global__ __launch_bounds__(256) void proj32_k(const float* __restrict__ x,
    const float* __restrict__ W, const float* __restrict__ bias,
    const float* __restrict__ a, float* __restrict__ out)
{
    __shared__ float Wl[32 * 128];
    int bf = blockIdx.x; int b = bf / NF, f = bf % NF;
    int t = blockIdx.y * 256 + threadIdx.x;
    for (int i = threadIdx.x; i < 32 * 128; i += 256) Wl[i] = W[i];
    __syncthreads();
    if (t >= NT) return;
    float acc[32];
#pragma unroll
    for (int o = 0; o < 32; o++) acc[o] = 0.f;
    const float* xp = x + (size_t)(b * NC * NF + f) * NT + t;
    for (int c = 0; c < NC; c++) {
        float xv = xp[(size_t)c * NF * NT];
#pragma unroll
        for (int o = 0; o < 32; o++) acc[o] += xv * Wl[o * 128 + c];
    }
    float av = a[0];
#pragma unroll
    for (int o = 0; o < 32; o++) {
        float y = acc[o] + bias[o];
        y = (y >= 0.f) ? y : av * y;
        int h = o >> 2, e = o & 3;
        out[(size_t)((b * NH + h) * DQ + f * NE + e) * NT + t] = y;
    }
}

// ---------------- V projection: 128 -> 128 (64 per block), PReLU, write [bh][d=f*16+v][t] ----------------
__global__ __launch_bounds__(256) void projV_k(const float* __restrict__ x,
    const float* __restrict__ W, const float* __restrict__ bias,
    const float* __restrict__ a, float* __restrict__ out)
{
    __shared__ float Wl[64 * 128];
    int bf = blockIdx.x; int b = bf / NF, f = bf % NF;
    int t = blockIdx.y * 256 + threadIdx.x;
    int o0 = blockIdx.z * 64;
    for (int i = threadIdx.x; i < 64 * 128; i += 256) Wl[i] = W[o0 * 128 + i];
    __syncthreads();
    if (t >= NT) return;
    float acc[64];
#pragma unroll
    for (int o = 0; o < 64; o++) acc[o] = 0.f;
    const float* xp = x + (size_t)(b * NC * NF + f) * NT + t;
    for (int c = 0; c < NC; c++) {
        float xv = xp[(size_t)c * NF * NT];
#pragma unroll
        for (int o = 0; o < 64; o++) acc[o] += xv * Wl[o * 128 + c];
    }
    float av = a[0];
#pragma unroll
    for (int o = 0; o < 64; o++) {
        int oo = o0 + o;
        float y = acc[o] + bias[oo];
        y = (y >= 0.f) ? y : av * y;
        int h = oo >> 4, v = oo & 15;
        out[(size_t)((b * NH + h) * DV + f * NV + v) * NT + t] = y;
    }
}

// ---------------- P projection: z(from VoT) 128 -> 128 (64 per block), PReLU, write yraw[b][o][f][t] ----------------
__global__ __launch_bounds__(256) void projP_k(const float* __restrict__ VoT,
    const float* __restrict__ W, const float* __restrict__ bias,
    const float* __restrict__ a, float* __restrict__ yraw)
{
    __shared__ float Wl[64 * 128];
    int bf = blockIdx.x; int b = bf / NF, f = bf % NF;
    int t = blockIdx.y * 256 + threadIdx.x;
    int o0 = blockIdx.z * 64;
    for (int i = threadIdx.x; i < 64 * 128; i += 256) Wl[i] = W[o0 * 128 + i];
    __syncthreads();
    if (t >= NT) return;
    float acc[64];
#pragma unroll
    for (int o = 0; o < 64; o++) acc[o] = 0.f;
    for (int cp = 0; cp < NC; cp++) {
        int h = cp >> 4, v = cp & 15;
        float zv = VoT[(size_t)((b * NH + h) * DV + f * NV + v) * NT + t];
#pragma unroll
        for (int o = 0; o < 64; o++) acc[o] += zv * Wl[o * 128 + cp];
    }
    float av = a[0];
#pragma unroll
    for (int o = 0; o < 64; o++) {
        int oo = o0 + o;
        float y = acc[o] + bias[oo];
        y = (y >= 0.f) ? y : av * y;
        yraw[(size_t)((b * NC + oo) * NF + f) * NT + t] = y;
    }
}

// ---------------- LN partial sums: per (bh, t, chunk) over d ----------------
__global__ __launch_bounds__(256) void ln_s1_k(const float* __restrict__ buf,
    float* __restrict__ pS, float* __restrict__ pS2, int D, int chunk, int nch)
{
    int bh = blockIdx.x;
    int t = blockIdx.y * 256 + threadIdx.x;
    if (t >= NT) return;
    int ch = blockIdx.z;
    int d0 = ch * chunk;
    int dn = min(chunk, D - d0);
    const float* p0 = buf + ((size_t)bh * D + d0) * NT + t;
    float s = 0.f, s2 = 0.f;
    for (int d = 0; d < dn; d++) { float v = p0[(size_t)d * NT]; s += v; s2 += v * v; }
    pS [(size_t)(bh * nch + ch) * NT + t] = s;
    pS2[(size_t)(bh * nch + ch) * NT + t] = s2;
}

// ---------------- LN apply (combine fused): in place ----------------
__global__ __launch_bounds__(256) void ln_apply_k(float* __restrict__ buf,
    const float* __restrict__ pS, const float* __restrict__ pS2,
    const float* __restrict__ g, const float* __restrict__ be,
    int D, int chunk, int nch)
{
    int bh = blockIdx.x;
    int t = blockIdx.y * 256 + threadIdx.x;
    if (t >= NT) return;
    float s = 0.f, s2 = 0.f;
    for (int i = 0; i < nch; i++) {
        s  += pS [(size_t)(bh * nch + i) * NT + t];
        s2 += pS2[(size_t)(bh * nch + i) * NT + t];
    }
    float inv = 1.0f / (float)D;
    float mu = s * inv;
    float var = s2 * inv - mu * mu;
    float rstd = rsqrtf(var + 1e-5f);
    int d0 = blockIdx.z * chunk;
    int dn = min(chunk, D - d0);
    float* p0 = buf + ((size_t)bh * D + d0) * NT + t;
    for (int d = 0; d < dn; d++) {
        float v = p0[(size_t)d * NT];
        p0[(size_t)d * NT] = (v - mu) * rstd * g[d0 + d] + be[d0 + d];
    }
}

// ---------------- K_buf_new / V_buf_new: last 9 time rows of LN'd K, V ----------------
__global__ void copybuf_k(const float* __restrict__ Kt, const float* __restrict__ Vt,
                          float* __restrict__ outK, float* __restrict__ outV)
{
    int i = blockIdx.x * 256 + threadIdx.x;
    const int NK = 32 * 9 * DQ;
    const int NVb = 32 * 9 * DV;
    if (i < NK) {
        int bh = i / (9 * DQ); int r = i % (9 * DQ); int j = r / DQ; int d = r % DQ;
        outK[i] = Kt[(size_t)(bh * DQ + d) * NT + 491 + j];
    } else if (i < NK + NVb) {
        int i2 = i - NK;
        int bh = i2 / (9 * DV); int r = i2 % (9 * DV); int j = r / DV; int d = r % DV;
        outV[i2] = Vt[(size_t)(bh * DV + d) * NT + 491 + j];
    }
}

// ---------------- scores partials over d-chunks: spart[ch][bh][c][t] ----------------
__global__ __launch_bounds__(256) void scores_s1_k(const float* __restrict__ Qt,
    const float* __restrict__ Kt, const float* __restrict__ Kbuf,
    float* __restrict__ spart, int chunk, int nch)
{
    int bh = blockIdx.x;
    int t = blockIdx.y * 256 + threadIdx.x;
    if (t >= NT) return;
    int ch = blockIdx.z;
    int d0 = ch * chunk;
    int dn = min(chunk, DQ - d0);
    float s[NCTX];
#pragma unroll
    for (int c = 0; c < NCTX; c++) s[c] = 0.f;
    const float* q = Qt + ((size_t)bh * DQ + d0) * NT + t;
    if (t >= NCTX - 1) {
        const float* kb = Kt + ((size_t)bh * DQ + d0) * NT + (t - (NCTX - 1));
        for (int d = 0; d < dn; d++) {
            float qv = q[(size_t)d * NT];
            const float* kr = kb + (size_t)d * NT;
#pragma unroll
            for (int c = 0; c < NCTX; c++) s[c] += qv * kr[c];
        }
    } else {
        for (int d = 0; d < dn; d++) {
            float qv = q[(size_t)d * NT];
#pragma unroll
            for (int c = 0; c < NCTX; c++) {
                int tc = t + c;
                float kv = (tc < NCTX - 1) ? Kbuf[(size_t)(bh * (NCTX - 1) + tc) * DQ + d0 + d]
                                           : Kt[(size_t)(bh * DQ + d0 + d) * NT + (tc - (NCTX - 1))];
                s[c] += qv * kv;
            }
        }
    }
#pragma unroll
    for (int c = 0; c < NCTX; c++)
        spart[(size_t)((ch * 32 + bh) * NCTX + c) * NT + t] = s[c];
}

// ---------------- combine + softmax: p[bh][c][t] ----------------
__global__ __launch_bounds__(256) void softmax_k(const float* __restrict__ spart,
    float* __restrict__ p, int nch)
{
    int bh = blockIdx.x;
    int t = blockIdx.y * 256 + threadIdx.x;
    if (t >= NT) return;
    float s[NCTX];
#pragma unroll
    for (int c = 0; c < NCTX; c++) s[c] = 0.f;
    for (int z = 0; z < nch; z++) {
#pragma unroll
        for (int c = 0; c < NCTX; c++)
            s[c] += spart[(size_t)((z * 32 + bh) * NCTX + c) * NT + t];
    }
    const float sc = 0.06201736729460423f; // 1/sqrt(260)
    float m = -1e30f;
#pragma unroll
    for (int c = 0; c < NCTX; c++) { s[c] *= sc; m = fmaxf(m, s[c]); }
    float den = 0.f;
#pragma unroll
    for (int c = 0; c < NCTX; c++) { s[c] = __expf(s[c] - m); den += s[c]; }
    float iden = 1.0f / den;
#pragma unroll
    for (int c = 0; c < NCTX; c++) p[(size_t)(bh * NCTX + c) * NT + t] = s[c] * iden;
}

// ---------------- Vo = sum_c p[c] * Vfull[t+c], d-chunked: VoT[bh][d][t] ----------------
__global__ __launch_bounds__(256) void vo_k(const float* __restrict__ p,
    const float* __restrict__ Vt, const float* __restrict__ Vbuf,
    float* __restrict__ VoT, int chunk)
{
    int bh = blockIdx.x;
    int t = blockIdx.y * 256 + threadIdx.x;
    if (t >= NT) return;
    int d0 = blockIdx.z * chunk;
    int dn = min(chunk, DV - d0);
    float pc[NCTX];
#pragma unroll
    for (int c = 0; c < NCTX; c++) pc[c] = p[(size_t)(bh * NCTX + c) * NT + t];
    if (t >= NCTX - 1) {
        const float* vb = Vt + ((size_t)bh * DV + d0) * NT + (t - (NCTX - 1));
        float* ob = VoT + ((size_t)bh * DV + d0) * NT + t;
        for (int d = 0; d < dn; d++) {
            const float* vr = vb + (size_t)d * NT;
            float acc = 0.f;
#pragma unroll
            for (int c = 0; c < NCTX; c++) acc += pc[c] * vr[c];
            ob[(size_t)d * NT] = acc;
        }
    } else {
        for (int d = 0; d < dn; d++) {
            float acc = 0.f;
#pragma unroll
            for (int c = 0; c < NCTX; c++) {
                int tc = t + c;
                float v = (tc < NCTX - 1) ? Vbuf[(size_t)(bh * (NCTX - 1) + tc) * DV + d0 + d]
                                          : Vt[(size_t)(bh * DV + d0 + d) * NT + (tc - (NCTX - 1))];
                acc += pc[c] * v;
            }
            VoT[(size_t)(bh * DV + d0 + d) * NT + t] = acc;
        }
    }
}

// ---------------- Final LN over 8320 (per b,t): partial sums, 64 chunks ----------------
__global__ __launch_bounds__(256) void lnp_s1(const float* __restrict__ yraw,
    float* __restrict__ partS, float* __restrict__ partS2)
{
    int b = blockIdx.x;
    int t = blockIdx.y * 256 + threadIdx.x;
    int ch = blockIdx.z;
    if (t >= NT) return;
    float s = 0.f, s2 = 0.f;
    int i0 = ch * 130;
    for (int k = 0; k < 130; k++) {
        int i = i0 + k;
        int f = i >> 7, o = i & 127;
        float v = yraw[(size_t)((b * NC + o) * NF + f) * NT + t];
        s += v; s2 += v * v;
    }
    partS [(size_t)(b * 64 + ch) * NT + t] = s;
    partS2[(size_t)(b * 64 + ch) * NT + t] = s2;
}

__global__ __launch_bounds__(256) void lnp_s2(const float* __restrict__ partS,
    const float* __restrict__ partS2, float* __restrict__ muA, float* __restrict__ rstdA)
{
    int b = blockIdx.x;
    int t = blockIdx.y * 256 + threadIdx.x;
    if (t >= NT) return;
    float s = 0.f, s2 = 0.f;
    for (int ch = 0; ch < 64; ch++) {
        s  += partS [(size_t)(b * 64 + ch) * NT + t];
        s2 += partS2[(size_t)(b * 64 + ch) * NT + t];
    }
    float inv = 1.0f / (float)DP;
    float mu = s * inv;
    float var = s2 * inv - mu * mu;
    muA[b * NT + t] = mu;
    rstdA[b * NT + t] = rsqrtf(var + 1e-5f);
}

// ---------------- apply LN + residual, output [b][o][f][t] ----------------
__global__ __launch_bounds__(256) void lnp_apply(const float* __restrict__ yraw,
    const float* __restrict__ x, const float* __restrict__ g, const float* __restrict__ be,
    const float* __restrict__ muA, const float* __restrict__ rstdA, float* __restrict__ out)
{
    int bo = blockIdx.x; int b = bo >> 7, o = bo & 127;
    int t = blockIdx.y * 256 + threadIdx.x;
    if (t >= NT) return;
    float mu = muA[b * NT + t], rstd = rstdA[b * NT + t];
    for (int f = 0; f < NF; f++) {
        size_t idx = (size_t)((b * NC + o) * NF + f) * NT + t;
        int i = f * NC + o;
        float v = yraw[idx];
        out[idx] = (v - mu) * rstd * g[i] + be[i] + x[idx];
    }
}

extern "C" void kernel_launch(void* const* d_in, const int* in_sizes, int n_in,
                              void* d_out, int out_size, void* d_ws, size_t ws_size,
                              hipStream_t stream) {
    const float* x    = (const float*)d_in[0];
    const float* mc   = (const float*)d_in[1];
    const float* Kbuf = (const float*)d_in[2];
    const float* Vbuf = (const float*)d_in[3];
    const float* W_Q  = (const float*)d_in[4];
    const float* b_Q  = (const float*)d_in[5];
    const float* a_Q  = (const float*)d_in[6];
    const float* g_Q  = (const float*)d_in[7];
    const float* be_Q = (const float*)d_in[8];
    const float* W_K  = (const float*)d_in[9];
    const float* b_K  = (const float*)d_in[10];
    const float* a_K  = (const float*)d_in[11];
    const float* g_K  = (const float*)d_in[12];
    const float* be_K = (const float*)d_in[13];
    const float* W_V  = (const float*)d_in[14];
    const float* b_V  = (const float*)d_in[15];
    const float* a_V  = (const float*)d_in[16];
    const float* g_V  = (const float*)d_in[17];
    const float* be_V = (const float*)d_in[18];
    const float* W_P  = (const float*)d_in[19];
    const float* b_P  = (const float*)d_in[20];
    const float* a_P  = (const float*)d_in[21];
    const float* g_P  = (const float*)d_in[22];
    const float* be_P = (const float*)d_in[23];

    float* out  = (float*)d_out;                       // (4,128,65,500)
    float* outK = out + (size_t)NB * NC * NF * NT;     // +16,640,000
    float* outV = outK + 32 * 9 * DQ;                  // +74,880

    float* ws = (float*)d_ws;
    float* Qt   = ws;                                  // 4,160,000
    float* Kt   = Qt + (size_t)32 * DQ * NT;           // 4,160,000
    float* Vt   = Kt + (size_t)32 * DQ * NT;           // 16,640,000
    float* VoT  = Vt + (size_t)32 * DV * NT;           // 16,640,000
    float* pbuf = VoT + (size_t)32 * DV * NT;          // 160,000
    float* yraw = Vt;  // alias: Vt dead after vo_k

    // Scratch partials all alias the VoT region (dead at those points):
    //  - LN partials used before vo_k writes VoT
    //  - scores partials consumed by softmax_k before vo_k
    //  - lnp partials used after projP_k's last read of VoT
    float* scr = VoT;
    float* lnS  = scr;            // up to 208,000
    float* lnS2 = scr + 210000;   // up to 208,000
    float* spart = scr;           // 800,000 (5*32*10*500)
    float* lpS  = scr;            // 128,000
    float* lpS2 = scr + 130000;   // 128,000
    float* muA  = scr + 262000;   // 2,000
    float* rstdA= scr + 264000;   // 2,000

    dim3 blk(256);
    const int TCH = (NT + 255) / 256;  // 2

    proj32_k<<<dim3(NB * NF, TCH), blk, 0, stream>>>(x,  W_Q, b_Q, a_Q, Qt);
    proj32_k<<<dim3(NB * NF, TCH), blk, 0, stream>>>(mc, W_K, b_K, a_K, Kt);
    projV_k <<<dim3(NB * NF, TCH, 2), blk, 0, stream>>>(mc, W_V, b_V, a_V, Vt);

    // LN Q (D=260: 5 chunks of 52)
    ln_s1_k   <<<dim3(32, TCH, 5), blk, 0, stream>>>(Qt, lnS, lnS2, DQ, 52, 5);
    ln_apply_k<<<dim3(32, TCH, 5), blk, 0, stream>>>(Qt, lnS, lnS2, g_Q, be_Q, DQ, 52, 5);
    // LN K
    ln_s1_k   <<<dim3(32, TCH, 5), blk, 0, stream>>>(Kt, lnS, lnS2, DQ, 52, 5);
    ln_apply_k<<<dim3(32, TCH, 5), blk, 0, stream>>>(Kt, lnS, lnS2, g_K, be_K, DQ, 52, 5);
    // LN V (D=1040: 13 chunks of 80)
    ln_s1_k   <<<dim3(32, TCH, 13), blk, 0, stream>>>(Vt, lnS, lnS2, DV, 80, 13);
    ln_apply_k<<<dim3(32, TCH, 13), blk, 0, stream>>>(Vt, lnS, lnS2, g_V, be_V, DV, 80, 13);

    int nbuf = 32 * 9 * DQ + 32 * 9 * DV;
    copybuf_k<<<dim3((nbuf + 255) / 256), blk, 0, stream>>>(Kt, Vt, outK, outV);

    scores_s1_k<<<dim3(32, TCH, 5), blk, 0, stream>>>(Qt, Kt, Kbuf, spart, 52, 5);
    softmax_k  <<<dim3(32, TCH), blk, 0, stream>>>(spart, pbuf, 5);
    vo_k       <<<dim3(32, TCH, 13), blk, 0, stream>>>(pbuf, Vt, Vbuf, VoT, 80);

    projP_k<<<dim3(NB * NF, TCH, 2), blk, 0, stream>>>(VoT, W_P, b_P, a_P, yraw);

    lnp_s1   <<<dim3(NB, TCH, 64), blk, 0, stream>>>(yraw, lpS, lpS2);
    lnp_s2   <<<dim3(NB, TCH), blk, 0, stream>>>(lpS, lpS2, muA, rstdA);
    lnp_apply<<<dim3(NB * NC, TCH), blk, 0, stream>>>(yraw, x, g_P, be_P, muA, rstdA, out);
}